// Round 13
// baseline (414.388 us; speedup 1.0000x reference)
//
#include <hip/hip_runtime.h>
#include <hip/hip_bf16.h>

#define NN 5000
#define TT 10
#define FOUT 8
#define HH 64
#define EE 80000
#define LL 4

#define STR1 136            // K=128 weight pack k-stride (u16)
#define STR2 72             // K=64 weight pack k-stride (u16)

// edge wpack section offsets (u16, per layer) — LDS [col][k] pack
#define EWT1 0              // 64*136 = 8704 : edge_w1 rows 0..127 [col][k]
#define EWT2 8704           // 64*72  = 4608 : edge_w2 [col][k]
#define ECT1 13312          // 64*72  = 4608 : coord_w1 [col][k]
#define ETL1 17920          // 64*8   = 512  : [col][8] = {w_rad, w_ea0, w_ea1, b1, 0..}
#define ETB2 18432          // 64*8   = 512  : {b2, 0..}
#define ETC1 18944          // 64*8   = 512  : {cb1, 0..}
#define EDGE_WPACK 19456    // u16 per layer (38912 B)

// node wpack sections
#define NWT1 0              // 8704 : node_w1 [col][k]; k in [64,128) sigma-permuted
#define NWT2 8704           // 4608 : node_w2 [col][k]
#define NTL1 13312          // 512  : {nb1,0..}
#define NTL2 13824          // 512  : {nb2,0..}
#define NODE_WPACK 14336    // u16 per layer (28672 B)

typedef __attribute__((ext_vector_type(8))) short short8;
typedef __attribute__((ext_vector_type(16))) float f32x16;

union FragU { short8 s; unsigned u[4]; unsigned short h[8]; };

__device__ __forceinline__ float silu_f(float x) {
    float e = __expf(-x);
    return x * __builtin_amdgcn_rcpf(1.0f + e);
}
// quad-batched silu: one v_rcp per 4 values (trans count 8 -> 5 per quad).
// clamp x>=-15 before exp so d<=3.3e6 and the quad product stays finite;
// for x<-15 returns x*rcp(huge) ~ 1e-5-accurate vs true silu (~0).
__device__ __forceinline__ void silu4(const float x0, const float x1,
                                      const float x2, const float x3,
                                      float s[4]) {
    float d0 = 1.0f + __expf(-fmaxf(x0, -15.0f));
    float d1 = 1.0f + __expf(-fmaxf(x1, -15.0f));
    float d2 = 1.0f + __expf(-fmaxf(x2, -15.0f));
    float d3 = 1.0f + __expf(-fmaxf(x3, -15.0f));
    float p01 = d0 * d1, p23 = d2 * d3;
    float r = __builtin_amdgcn_rcpf(p01 * p23);
    float r01 = r * p23, r23 = r * p01;
    s[0] = x0 * (d1 * r01);
    s[1] = x1 * (d0 * r01);
    s[2] = x2 * (d3 * r23);
    s[3] = x3 * (d2 * r23);
}
__device__ __forceinline__ float bf2f(unsigned short u) {
    return __uint_as_float(((unsigned int)u) << 16);
}
__device__ __forceinline__ unsigned short f2bf(float x) {   // RNE
    unsigned int u = __float_as_uint(x);
    u += 0x7fffu + ((u >> 16) & 1u);
    return (unsigned short)(u >> 16);
}
__device__ __forceinline__ unsigned pkbf(float lo, float hi) {
    unsigned r;
    asm("v_cvt_pk_bf16_f32 %0, %1, %2" : "=v"(r) : "v"(lo), "v"(hi));
    return r;
}
__device__ __forceinline__ void plswap(unsigned &a, unsigned &b) {
    asm("v_permlane32_swap_b32 %0, %1" : "+v"(a), "+v"(b));
}

// silu (quad-batched) + pack C-layout accs into u[mt][2q+h]
__device__ __forceinline__ void pack_silu(const f32x16& a0, const f32x16& a1, unsigned u[2][8]) {
    #pragma unroll
    for (int q = 0; q < 4; q++) {
        float s[4];
        silu4(a0[4*q], a0[4*q+1], a0[4*q+2], a0[4*q+3], s);
        u[0][2*q]   = pkbf(s[0], s[1]);
        u[0][2*q+1] = pkbf(s[2], s[3]);
        silu4(a1[4*q], a1[4*q+1], a1[4*q+2], a1[4*q+3], s);
        u[1][2*q]   = pkbf(s[0], s[1]);
        u[1][2*q+1] = pkbf(s[2], s[3]);
    }
}
__device__ __forceinline__ void pack_raw(const f32x16& a0, const f32x16& a1, unsigned u[2][8]) {
    #pragma unroll
    for (int q = 0; q < 4; q++) {
        #pragma unroll
        for (int h = 0; h < 2; h++) {
            u[0][2*q+h] = pkbf(a0[4*q+2*h], a0[4*q+2*h+1]);
            u[1][2*q+h] = pkbf(a1[4*q+2*h], a1[4*q+2*h+1]);
        }
    }
}
__device__ __forceinline__ void exch(unsigned u[2][8], short8 bx[4]) {
    #pragma unroll
    for (int kt = 0; kt < 4; kt++) {
        const int m = kt >> 1, kk = kt & 1;
        unsigned X  = u[m][4*kk],     Y  = u[m][4*kk+2];
        unsigned X2 = u[m][4*kk+1],   Y2 = u[m][4*kk+3];
        plswap(X, Y);
        plswap(X2, Y2);
        FragU f; f.u[0] = X; f.u[1] = X2; f.u[2] = Y; f.u[3] = Y2;
        bx[kt] = f.s;
    }
}

// ---------------------------------------------------------------- init (vectorized: 8 cols/thread)
__global__ __launch_bounds__(256) void k_init_h(
    const float* __restrict__ h_in, const float* __restrict__ emb_w,
    const float* __restrict__ emb_b, const float* __restrict__ time_emb,
    unsigned short* __restrict__ hbuf)
{
    int idx = blockIdx.x * 256 + threadIdx.x;   // over N*T*8
    if (idx >= NN * TT * 8) return;
    int g  = idx & 7;
    int nt = idx >> 3;
    int t  = nt % TT;
    int n  = nt / TT;
    int j0 = g * 8;
    float hv = h_in[n];
    short8 o;
    #pragma unroll
    for (int jj = 0; jj < 8; jj++) {
        float val = hv * emb_w[j0 + jj] + emb_b[j0 + jj] + time_emb[t * 64 + j0 + jj];
        o[jj] = (short)f2bf(val);
    }
    *(short8*)(hbuf + (size_t)nt * 64 + j0) = o;
}

// also zeroes deg[] (runs before k_deg)
__global__ __launch_bounds__(256) void k_init_coord(
    const float* __restrict__ x, float* __restrict__ coord, int* __restrict__ deg)
{
    int i = blockIdx.x * 256 + threadIdx.x;
    if (i >= NN * TT) return;
    if (i < NN) deg[i] = 0;
    int t = i % TT, n = i / TT;
    const float* src = x + (size_t)(t * NN + n) * 3;
    float4 v;
    v.x = src[0]; v.y = src[1]; v.z = src[2]; v.w = 0.0f;
    *(float4*)(coord + (size_t)i * 4) = v;
}

// ---------------------------------------------------------------- weight prep (LDS-order pack)
__global__ __launch_bounds__(256) void k_prep(
    const float* __restrict__ ew1, const float* __restrict__ eb1,
    const float* __restrict__ ew2, const float* __restrict__ eb2,
    const float* __restrict__ cw1, const float* __restrict__ cb1,
    const float* __restrict__ nw1, const float* __restrict__ nb1,
    const float* __restrict__ nw2, const float* __restrict__ nb2,
    unsigned short* __restrict__ wpack)
{
    const int ETOT = LL * EDGE_WPACK;
    const int TOT  = ETOT + LL * NODE_WPACK;
    int idx = blockIdx.x * 256 + threadIdx.x;
    if (idx >= TOT) return;
    float v = 0.0f;
    if (idx < ETOT) {
        int l = idx / EDGE_WPACK, o = idx % EDGE_WPACK;
        if (o < EWT2) {
            int cc = o / STR1, k = o % STR1;
            if (k < 128) v = ew1[(size_t)l * 131 * 64 + (size_t)k * 64 + cc];
        } else if (o < ECT1) {
            int o2 = o - EWT2; int cc = o2 / STR2, k = o2 % STR2;
            if (k < 64) v = ew2[(size_t)l * 4096 + (size_t)k * 64 + cc];
        } else if (o < ETL1) {
            int o2 = o - ECT1; int cc = o2 / STR2, k = o2 % STR2;
            if (k < 64) v = cw1[(size_t)l * 4096 + (size_t)k * 64 + cc];
        } else if (o < ETB2) {
            int o2 = o - ETL1; int cc = o2 >> 3, j = o2 & 7;
            if (j == 0) v = ew1[(size_t)l * 131 * 64 + 128 * 64 + cc];
            else if (j == 1) v = ew1[(size_t)l * 131 * 64 + 129 * 64 + cc];
            else if (j == 2) v = ew1[(size_t)l * 131 * 64 + 130 * 64 + cc];
            else if (j == 3) v = eb1[l * 64 + cc];
        } else if (o < ETC1) {
            int o2 = o - ETB2; int cc = o2 >> 3, j = o2 & 7;
            if (j == 0) v = eb2[l * 64 + cc];
        } else {
            int o2 = o - ETC1; int cc = o2 >> 3, j = o2 & 7;
            if (j == 0) v = cb1[l * 64 + cc];
        }
    } else {
        int q = idx - ETOT;
        int l = q / NODE_WPACK, o = q % NODE_WPACK;
        if (o < NWT2) {
            int cc = o / STR1, k = o % STR1;
            if (k < 64) {
                v = nw1[(size_t)l * 8192 + (size_t)k * 64 + cc];
            } else if (k < 128) {
                int p = k - 64;
                int gp = p >> 5, mt = (p >> 4) & 1, reg = p & 15;
                int j = mt * 32 + (reg & 3) + 8 * (reg >> 2) + 4 * gp;
                v = nw1[(size_t)l * 8192 + (size_t)(64 + j) * 64 + cc];
            }
        } else if (o < NTL1) {
            int o2 = o - NWT2; int cc = o2 / STR2, k = o2 % STR2;
            if (k < 64) v = nw2[(size_t)l * 4096 + (size_t)k * 64 + cc];
        } else if (o < NTL2) {
            int o2 = o - NTL1; int cc = o2 >> 3, j = o2 & 7;
            if (j == 0) v = nb1[l * 64 + cc];
        } else {
            int o2 = o - NTL2; int cc = o2 >> 3, j = o2 & 7;
            if (j == 0) v = nb2[l * 64 + cc];
        }
    }
    wpack[idx] = f2bf(v);
}

// ---------------------------------------------------------------- CSR build
__global__ __launch_bounds__(256) void k_deg(
    const int* __restrict__ edges, int* __restrict__ deg)
{
    int e = blockIdx.x * 256 + threadIdx.x;
    if (e >= EE) return;
    atomicAdd(deg + edges[e], 1);
}

__global__ __launch_bounds__(256) void k_scan(
    const int* __restrict__ deg, int* __restrict__ rowptr, int* __restrict__ woff)
{
    __shared__ int sums[256];
    int tid = threadIdx.x;
    const int CH = (NN + 255) / 256;  // 20
    int base = tid * CH;
    int s = 0;
    for (int i = 0; i < CH; i++) {
        int idx = base + i;
        if (idx < NN) s += deg[idx];
    }
    sums[tid] = s;
    __syncthreads();
    for (int off = 1; off < 256; off <<= 1) {
        int other = (tid >= off) ? sums[tid - off] : 0;
        __syncthreads();
        sums[tid] += other;
        __syncthreads();
    }
    int run = sums[tid] - s;
    for (int i = 0; i < CH; i++) {
        int idx = base + i;
        if (idx < NN) {
            rowptr[idx] = run;
            woff[idx] = run;
            run += deg[idx];
        }
    }
    if (tid == 255) rowptr[NN] = run;
}

__global__ __launch_bounds__(256) void k_scatter(
    const int* __restrict__ edges, int* __restrict__ woff, int* __restrict__ eidx)
{
    int e = blockIdx.x * 256 + threadIdx.x;
    if (e >= EE) return;
    int pos = atomicAdd(woff + edges[e], 1);
    eidx[pos] = e;
}

// ---------------------------------------------------------------- edge MLP, 32x32x16 MFMA, LDS weights, T-paired
// grid (EE/128, TT/2): each wave does 32 edges x 2 timesteps; every weight ds_read feeds 2 MFMAs.
__global__ __launch_bounds__(256) void k_edge_mfma(
    const unsigned short* __restrict__ hbuf,  // bf16 [N*T][64]
    const float* __restrict__ coord,          // [N*T][4]
    const int* __restrict__ edges,
    const float* __restrict__ eattr,
    const unsigned short* __restrict__ wpack, // this layer's packed weights
    const float* __restrict__ cw2v,           // [64] f32
    unsigned char* __restrict__ mbuf8,        // fp8 e4m3 [E*T][64] (sigma-order)
    float* __restrict__ trans4)               // f32 [E*T][4]
{
    __shared__ __align__(16) unsigned short w_lds[EDGE_WPACK];
    __shared__ float cw2_lds[64];
    int tid = threadIdx.x;
    {
        const uint4* src = (const uint4*)wpack;
        uint4* dst = (uint4*)w_lds;
        #pragma unroll
        for (int i = 0; i < 10; i++) {
            int p = i * 256 + tid;
            if (p < EDGE_WPACK / 8) dst[p] = src[p];
        }
        if (tid < 64) cw2_lds[tid] = cw2v[tid];
    }
    __syncthreads();

    int wave = tid >> 6, lane = tid & 63;
    int gp = lane >> 5, c = lane & 31;
    bool g0 = (gp == 0);

    int e = blockIdx.x * 128 + wave * 32 + c;
    int t0 = blockIdx.y * 2;
    int rn = edges[e], cn = edges[EE + e];
    int rt0 = rn * TT + t0, ct0 = cn * TT + t0;
    int rt1 = rt0 + 1,      ct1 = ct0 + 1;

    float4 cr0 = *(const float4*)(coord + (size_t)rt0 * 4);
    float4 cl0 = *(const float4*)(coord + (size_t)ct0 * 4);
    float4 cr1 = *(const float4*)(coord + (size_t)rt1 * 4);
    float4 cl1 = *(const float4*)(coord + (size_t)ct1 * 4);
    float d00 = cr0.x - cl0.x, d01 = cr0.y - cl0.y, d02 = cr0.z - cl0.z;
    float d10 = cr1.x - cl1.x, d11 = cr1.y - cl1.y, d12 = cr1.z - cl1.z;
    float rad0 = d00 * d00 + d01 * d01 + d02 * d02;
    float rad1 = d10 * d10 + d11 * d11 + d12 * d12;
    float2 ea = *(const float2*)(eattr + 2 * e);

    const unsigned short* hr0 = hbuf + (size_t)rt0 * 64;
    const unsigned short* hc0 = hbuf + (size_t)ct0 * 64;
    const unsigned short* hr1 = hbuf + (size_t)rt1 * 64;
    const unsigned short* hc1 = hbuf + (size_t)ct1 * 64;
    short8 bh0[8], bh1[8];
    #pragma unroll
    for (int kt = 0; kt < 4; kt++) {
        bh0[kt]     = *(const short8*)(hr0 + kt * 16 + gp * 8);
        bh0[4 + kt] = *(const short8*)(hc0 + kt * 16 + gp * 8);
        bh1[kt]     = *(const short8*)(hr1 + kt * 16 + gp * 8);
        bh1[4 + kt] = *(const short8*)(hc1 + kt * 16 + gp * 8);
    }

    FragU btail0, btail1, bone;
    btail0.u[0] = btail0.u[1] = btail0.u[2] = btail0.u[3] = 0;
    btail1.u[0] = btail1.u[1] = btail1.u[2] = btail1.u[3] = 0;
    bone.u[0] = bone.u[1] = bone.u[2] = bone.u[3] = 0;
    if (g0) {
        btail0.u[0] = pkbf(rad0, ea.x); btail0.u[1] = pkbf(ea.y, 1.0f);
        btail1.u[0] = pkbf(rad1, ea.x); btail1.u[1] = pkbf(ea.y, 1.0f);
        bone.u[0] = 0x3F80u;
    }

    // ---- layer 1: K=128 + tail tile; each af ds_read feeds t0 and t1 ----
    f32x16 a0[2], a1[2];
    {
        f32x16 z = {};
        a0[0] = z; a0[1] = z; a1[0] = z; a1[1] = z;
    }
    #pragma unroll
    for (int kt = 0; kt < 8; kt++) {
        #pragma unroll
        for (int mt = 0; mt < 2; mt++) {
            short8 af = *(const short8*)&w_lds[EWT1 + (mt * 32 + c) * STR1 + kt * 16 + gp * 8];
            a0[mt] = __builtin_amdgcn_mfma_f32_32x32x16_bf16(af, bh0[kt], a0[mt], 0, 0, 0);
            a1[mt] = __builtin_amdgcn_mfma_f32_32x32x16_bf16(af, bh1[kt], a1[mt], 0, 0, 0);
        }
    }
    #pragma unroll
    for (int mt = 0; mt < 2; mt++) {
        short8 af = *(const short8*)&w_lds[ETL1 + (mt * 32 + c) * 8];
        a0[mt] = __builtin_amdgcn_mfma_f32_32x32x16_bf16(af, btail0.s, a0[mt], 0, 0, 0);
        a1[mt] = __builtin_amdgcn_mfma_f32_32x32x16_bf16(af, btail1.s, a1[mt], 0, 0, 0);
    }

    unsigned u[2][8];
    short8 bx0[4], bx1[4];
    pack_silu(a0[0], a0[1], u);
    exch(u, bx0);
    pack_silu(a1[0], a1[1], u);
    exch(u, bx1);

    // ---- layer 2: K=64 + bias tile ----
    f32x16 b0[2], b1[2];
    {
        f32x16 z = {};
        b0[0] = z; b0[1] = z; b1[0] = z; b1[1] = z;
    }
    #pragma unroll
    for (int kt = 0; kt < 4; kt++) {
        #pragma unroll
        for (int mt = 0; mt < 2; mt++) {
            short8 af = *(const short8*)&w_lds[EWT2 + (mt * 32 + c) * STR2 + kt * 16 + gp * 8];
            b0[mt] = __builtin_amdgcn_mfma_f32_32x32x16_bf16(af, bx0[kt], b0[mt], 0, 0, 0);
            b1[mt] = __builtin_amdgcn_mfma_f32_32x32x16_bf16(af, bx1[kt], b1[mt], 0, 0, 0);
        }
    }
    #pragma unroll
    for (int mt = 0; mt < 2; mt++) {
        short8 af = *(const short8*)&w_lds[ETB2 + (mt * 32 + c) * 8];
        b0[mt] = __builtin_amdgcn_mfma_f32_32x32x16_bf16(af, bone.s, b0[mt], 0, 0, 0);
        b1[mt] = __builtin_amdgcn_mfma_f32_32x32x16_bf16(af, bone.s, b1[mt], 0, 0, 0);
    }

    // ---- silu(m) via quad-rcp, b3 frags + fp8 store, per t ----
    short8 b30[4], b31[4];
    {
        float sv[2][16];
        #pragma unroll
        for (int mt = 0; mt < 2; mt++)
            #pragma unroll
            for (int q = 0; q < 4; q++)
                silu4(b0[mt][4*q], b0[mt][4*q+1], b0[mt][4*q+2], b0[mt][4*q+3], &sv[mt][4*q]);
        #pragma unroll
        for (int q = 0; q < 4; q++)
            #pragma unroll
            for (int h = 0; h < 2; h++) {
                u[0][2*q+h] = pkbf(sv[0][4*q+2*h], sv[0][4*q+2*h+1]);
                u[1][2*q+h] = pkbf(sv[1][4*q+2*h], sv[1][4*q+2*h+1]);
            }
        exch(u, b30);
        unsigned w8[8];
        #pragma unroll
        for (int mt = 0; mt < 2; mt++)
            #pragma unroll
            for (int q = 0; q < 4; q++) {
                unsigned v = __builtin_amdgcn_cvt_pk_fp8_f32(sv[mt][4*q],   sv[mt][4*q+1], 0, false);
                v          = __builtin_amdgcn_cvt_pk_fp8_f32(sv[mt][4*q+2], sv[mt][4*q+3], v, true);
                w8[mt * 4 + q] = v;
            }
        unsigned char* mp8 = mbuf8 + ((size_t)e * TT + t0) * 64 + gp * 32;
        *(uint4*)(mp8)      = *(uint4*)&w8[0];
        *(uint4*)(mp8 + 16) = *(uint4*)&w8[4];
    }
    {
        float sv[2][16];
        #pragma unroll
        for (int mt = 0; mt < 2; mt++)
            #pragma unroll
            for (int q = 0; q < 4; q++)
                silu4(b1[mt][4*q], b1[mt][4*q+1], b1[mt][4*q+2], b1[mt][4*q+3], &sv[mt][4*q]);
        #pragma unroll
        for (int q = 0; q < 4; q++)
            #pragma unroll
            for (int h = 0; h < 2; h++) {
                u[0][2*q+h] = pkbf(sv[0][4*q+2*h], sv[0][4*q+2*h+1]);
                u[1][2*q+h] = pkbf(sv[1][4*q+2*h], sv[1][4*q+2*h+1]);
            }
        exch(u, b31);
        unsigned w8[8];
        #pragma unroll
        for (int mt = 0; mt < 2; mt++)
            #pragma unroll
            for (int q = 0; q < 4; q++) {
                unsigned v = __builtin_amdgcn_cvt_pk_fp8_f32(sv[mt][4*q],   sv[mt][4*q+1], 0, false);
                v          = __builtin_amdgcn_cvt_pk_fp8_f32(sv[mt][4*q+2], sv[mt][4*q+3], v, true);
                w8[mt * 4 + q] = v;
            }
        unsigned char* mp8 = mbuf8 + ((size_t)e * TT + t0 + 1) * 64 + gp * 32;
        *(uint4*)(mp8)      = *(uint4*)&w8[0];
        *(uint4*)(mp8 + 16) = *(uint4*)&w8[4];
    }

    // ---- coord MLP, shared ds_reads ----
    f32x16 c0[2], c1[2];
    {
        f32x16 z = {};
        c0[0] = z; c0[1] = z; c1[0] = z; c1[1] = z;
    }
    #pragma unroll
    for (int kt = 0; kt < 4; kt++) {
        #pragma unroll
        for (int mt = 0; mt < 2; mt++) {
            short8 af = *(const short8*)&w_lds[ECT1 + (mt * 32 + c) * STR2 + kt * 16 + gp * 8];
            c0[mt] = __builtin_amdgcn_mfma_f32_32x32x16_bf16(af, b30[kt], c0[mt], 0, 0, 0);
            c1[mt] = __builtin_amdgcn_mfma_f32_32x32x16_bf16(af, b31[kt], c1[mt], 0, 0, 0);
        }
    }
    #pragma unroll
    for (int mt = 0; mt < 2; mt++) {
        short8 af = *(const short8*)&w_lds[ETC1 + (mt * 32 + c) * 8];
        c0[mt] = __builtin_amdgcn_mfma_f32_32x32x16_bf16(af, bone.s, c0[mt], 0, 0, 0);
        c1[mt] = __builtin_amdgcn_mfma_f32_32x32x16_bf16(af, bone.s, c1[mt], 0, 0, 0);
    }
    float p0 = 0.0f, p1 = 0.0f;
    #pragma unroll
    for (int mt = 0; mt < 2; mt++) {
        #pragma unroll
        for (int q = 0; q < 4; q++) {
            float4 w4 = *(const float4*)&cw2_lds[mt * 32 + 8 * q + 4 * gp];
            float s[4];
            silu4(c0[mt][4*q], c0[mt][4*q+1], c0[mt][4*q+2], c0[mt][4*q+3], s);
            p0 += s[0] * w4.x + s[1] * w4.y + s[2] * w4.z + s[3] * w4.w;
            silu4(c1[mt][4*q], c1[mt][4*q+1], c1[mt][4*q+2], c1[mt][4*q+3], s);
            p1 += s[0] * w4.x + s[1] * w4.y + s[2] * w4.z + s[3] * w4.w;
        }
    }
    p0 += __shfl_xor(p0, 32);
    p1 += __shfl_xor(p1, 32);
    if (g0) {
        float4 o0; o0.x = d00 * p0; o0.y = d01 * p0; o0.z = d02 * p0; o0.w = 0.0f;
        float4 o1; o1.x = d10 * p1; o1.y = d11 * p1; o1.z = d12 * p1; o1.w = 0.0f;
        *(float4*)(trans4 + ((size_t)e * TT + t0) * 4)     = o0;
        *(float4*)(trans4 + ((size_t)e * TT + t0 + 1) * 4) = o1;
    }
}

// ---------------------------------------------------------------- gather: wave per node, all T fused (4-unrolled)
__global__ __launch_bounds__(256) void k_gather(
    const unsigned char* __restrict__ mbuf8, const float* __restrict__ trans4,
    const int* __restrict__ rowptr, const int* __restrict__ eidx,
    unsigned short* __restrict__ maggb, float* __restrict__ coord)
{
    int wv = __builtin_amdgcn_readfirstlane((int)(threadIdx.x >> 6));
    int lane = threadIdx.x & 63;
    int n = blockIdx.x * 4 + wv;
    int start = rowptr[n], end = rowptr[n + 1];

    bool ism = lane < 40;
    int tl = lane - 40; if (tl < 0) tl = 0; if (tl > 9) tl = 9;
    size_t moff = (size_t)lane * 16;
    size_t toff = (size_t)tl * 16;

    float acc[16];
    #pragma unroll
    for (int j = 0; j < 16; j++) acc[j] = 0.0f;
    float4 p4; p4.x = p4.y = p4.z = p4.w = 0.0f;

    int i = start;
    for (; i + 4 <= end; i += 4) {
        uint4 v[4];
        #pragma unroll
        for (int s = 0; s < 4; s++) {
            int ee = eidx[i + s];
            const char* a = ism ? (const char*)mbuf8 + (size_t)ee * 640 + moff
                                : (const char*)trans4 + (size_t)ee * 160 + toff;
            v[s] = *(const uint4*)a;
        }
        if (ism) {
            #pragma unroll
            for (int s = 0; s < 4; s++) {
                const unsigned* w0 = (const unsigned*)&v[s];
                #pragma unroll
                for (int w = 0; w < 4; w++) {
                    acc[w*4+0] += __builtin_amdgcn_cvt_f32_fp8(w0[w], 0);
                    acc[w*4+1] += __builtin_amdgcn_cvt_f32_fp8(w0[w], 1);
                    acc[w*4+2] += __builtin_amdgcn_cvt_f32_fp8(w0[w], 2);
                    acc[w*4+3] += __builtin_amdgcn_cvt_f32_fp8(w0[w], 3);
                }
            }
        } else {
            #pragma unroll
            for (int s = 0; s < 4; s++) {
                const float* f0 = (const float*)&v[s];
                p4.x += f0[0]; p4.y += f0[1]; p4.z += f0[2]; p4.w += f0[3];
            }
        }
    }
    for (; i < end; i++) {
        int e0 = eidx[i];
        const char* a0 = ism ? (const char*)mbuf8 + (size_t)e0 * 640 + moff
                             : (const char*)trans4 + (size_t)e0 * 160 + toff;
        uint4 v0 = *(const uint4*)a0;
        if (ism) {
            const unsigned* w0 = (const unsigned*)&v0;
            #pragma unroll
            for (int w = 0; w < 4; w++) {
                acc[w*4+0] += __builtin_amdgcn_cvt_f32_fp8(w0[w], 0);
                acc[w*4+1] += __builtin_amdgcn_cvt_f32_fp8(w0[w], 1);
                acc[w*4+2] += __builtin_amdgcn_cvt_f32_fp8(w0[w], 2);
                acc[w*4+3] += __builtin_amdgcn_cvt_f32_fp8(w0[w], 3);
            }
        } else {
            const float* f0 = (const float*)&v0;
            p4.x += f0[0]; p4.y += f0[1]; p4.z += f0[2]; p4.w += f0[3];
        }
    }

    if (ism) {
        unsigned w8[8];
        #pragma unroll
        for (int j = 0; j < 8; j++) w8[j] = pkbf(acc[2*j], acc[2*j+1]);
        unsigned short* dst = maggb + (size_t)n * 640 + lane * 16;
        *(uint4*)(dst)     = *(uint4*)&w8[0];
        *(uint4*)(dst + 8) = *(uint4*)&w8[4];
    } else if (lane < 50) {
        int t = lane - 40;
        float inv = 1.0f / fmaxf((float)(end - start), 1.0f);
        float* cp = coord + ((size_t)n * TT + t) * 4;
        float4 cv = *(float4*)cp;
        cv.x += p4.x * inv; cv.y += p4.y * inv; cv.z += p4.z * inv;
        *(float4*)cp = cv;
    }
}

// ---------------------------------------------------------------- node MLP, 32x32x16 MFMA, LDS weights
__global__ __launch_bounds__(256) void k_node_mfma(
    unsigned short* __restrict__ hbuf,
    const unsigned short* __restrict__ maggb,   // sigma-order (weights pre-permuted)
    const unsigned short* __restrict__ wpack)
{
    __shared__ __align__(16) unsigned short w_lds[NODE_WPACK];
    int tid = threadIdx.x;
    {
        const uint4* src = (const uint4*)wpack;
        uint4* dst = (uint4*)w_lds;
        #pragma unroll
        for (int i = 0; i < 7; i++) dst[i * 256 + tid] = src[i * 256 + tid];  // 1792 exact
    }
    __syncthreads();

    int wave = tid >> 6, lane = tid & 63;
    int gp = lane >> 5, c = lane & 31;
    bool g0 = (gp == 0);

    int idx = blockIdx.x * 128 + wave * 32 + c;
    bool valid = idx < NN * TT;
    int row = valid ? idx : 0;
    const unsigned short* hp = hbuf + (size_t)row * 64;
    const unsigned short* mp = maggb + (size_t)row * 64;
    short8 bh[8];
    #pragma unroll
    for (int kt = 0; kt < 4; kt++) bh[kt]     = *(const short8*)(hp + kt * 16 + gp * 8);
    #pragma unroll
    for (int kt = 0; kt < 4; kt++) bh[4 + kt] = *(const short8*)(mp + kt * 16 + gp * 8);
    FragU bone; bone.u[0] = bone.u[1] = bone.u[2] = bone.u[3] = 0;
    if (g0) bone.u[0] = 0x3F80u;

    f32x16 acc[2];
    {
        f32x16 z = {};
        acc[0] = z; acc[1] = z;
    }
    #pragma unroll
    for (int kt = 0; kt < 8; kt++) {
        #pragma unroll
        for (int mt = 0; mt < 2; mt++) {
            short8 af = *(const short8*)&w_lds[NWT1 + (mt * 32 + c) * STR1 + kt * 16 + gp * 8];
            acc[mt] = __builtin_amdgcn_mfma_f32_32x32x16_bf16(af, bh[kt], acc[mt], 0, 0, 0);
        }
    }
    #pragma unroll
    for (int mt = 0; mt < 2; mt++) {
        short8 af = *(const short8*)&w_lds[NTL1 + (mt * 32 + c) * 8];
        acc[mt] = __builtin_amdgcn_mfma_f32_32x32x16_bf16(af, bone.s, acc[mt], 0, 0, 0);
    }
    unsigned u[2][8];
    pack_silu(acc[0], acc[1], u);
    short8 bx[4];
    exch(u, bx);

    f32x16 acc2[2];
    {
        f32x16 z = {};
        acc2[0] = z; acc2[1] = z;
    }
    #pragma unroll
    for (int kt = 0; kt < 4; kt++) {
        #pragma unroll
        for (int mt = 0; mt < 2; mt++) {
            short8 af = *(const short8*)&w_lds[NWT2 + (mt * 32 + c) * STR2 + kt * 16 + gp * 8];
            acc2[mt] = __builtin_amdgcn_mfma_f32_32x32x16_bf16(af, bx[kt], acc2[mt], 0, 0, 0);
        }
    }
    #pragma unroll
    for (int mt = 0; mt < 2; mt++) {
        short8 af = *(const short8*)&w_lds[NTL2 + (mt * 32 + c) * 8];
        acc2[mt] = __builtin_amdgcn_mfma_f32_32x32x16_bf16(af, bone.s, acc2[mt], 0, 0, 0);
    }
    pack_raw(acc2[0], acc2[1], u);
    short8 o3[4];
    exch(u, o3);
    if (valid) {
        #pragma unroll
        for (int kt = 0; kt < 4; kt++) {
            FragU hv; hv.s = bh[kt];
            FragU of; of.s = o3[kt];
            FragU res;
            #pragma unroll
            for (int d = 0; d < 4; d++) {
                float a0 = bf2f(hv.h[2*d])   + bf2f((unsigned short)(of.u[d] & 0xFFFFu));
                float a1 = bf2f(hv.h[2*d+1]) + bf2f((unsigned short)(of.u[d] >> 16));
                res.u[d] = pkbf(a0, a1);
            }
            *(uint4*)(hbuf + (size_t)row * 64 + kt * 16 + gp * 8) = *(uint4*)res.u;
        }
    }
}

// ---------------------------------------------------------------- readout
__global__ __launch_bounds__(256) void k_final(
    const float* __restrict__ coord, const float* __restrict__ theta,
    float* __restrict__ out)
{
    int i = blockIdx.x * 256 + threadIdx.x;  // f*N + n
    if (i >= FOUT * NN) return;
    int f = i / NN, n = i % NN;

    float w[TT];
    float mx = -1e30f;
    #pragma unroll
    for (int t = 0; t < TT; t++) { w[t] = theta[f * TT + t]; mx = fmaxf(mx, w[t]); }
    float s = 0.0f;
    #pragma unroll
    for (int t = 0; t < TT; t++) { w[t] = __expf(w[t] - mx); s += w[t]; }
    float inv = 1.0f / s;
    float o0 = 0.f, o1 = 0.f, o2 = 0.f;
    #pragma unroll
    for (int t = 0; t < TT; t++) {
        float4 cv = *(const float4*)(coord + (size_t)(n * TT + t) * 4);
        float ww = w[t] * inv;
        o0 += ww * cv.x; o1 += ww * cv.y; o2 += ww * cv.z;
    }
    float* op = out + (size_t)(f * NN + n) * 3;
    op[0] = o0; op[1] = o1; op[2] = o2;
}

extern "C" void kernel_launch(void* const* d_in, const int* in_sizes, int n_in,
                              void* d_out, int out_size, void* d_ws, size_t ws_size,
                              hipStream_t stream)
{
    const float* h_in     = (const float*)d_in[0];
    const float* x        = (const float*)d_in[1];
    const int*   edges    = (const int*)d_in[2];
    const float* eattr    = (const float*)d_in[3];
    const float* emb_w    = (const float*)d_in[4];
    const float* emb_b    = (const float*)d_in[5];
    const float* time_emb = (const float*)d_in[6];
    const float* theta    = (const float*)d_in[7];
    const float* ew1 = (const float*)d_in[8];
    const float* eb1 = (const float*)d_in[9];
    const float* ew2 = (const float*)d_in[10];
    const float* eb2 = (const float*)d_in[11];
    const float* nw1 = (const float*)d_in[12];
    const float* nb1 = (const float*)d_in[13];
    const float* nw2 = (const float*)d_in[14];
    const float* nb2 = (const float*)d_in[15];
    const float* cw1 = (const float*)d_in[16];
    const float* cb1 = (const float*)d_in[17];
    const float* cw2 = (const float*)d_in[18];
    float* out = (float*)d_out;

    // ---- workspace carve ----
    char* wsb = (char*)d_ws;
    unsigned short* hbuf  = (unsigned short*)wsb;  wsb += (size_t)NN * TT * HH * 2;
    unsigned short* maggb = (unsigned short*)wsb;  wsb += (size_t)NN * TT * HH * 2;
    float* coord = (float*)wsb;                    wsb += (size_t)NN * TT * 4 * 4;
    unsigned char* mbuf8 = (unsigned char*)wsb;    wsb += (size_t)EE * TT * HH;      // fp8
    float* trans4 = (float*)wsb;                   wsb += (size_t)EE * TT * 4 * 4;
    unsigned short* wpack = (unsigned short*)wsb;  wsb += (size_t)LL * (EDGE_WPACK + NODE_WPACK) * 2;
    int* deg    = (int*)wsb;                       wsb += (size_t)NN * 4;
    int* rowptr = (int*)wsb;                       wsb += (size_t)(NN + 1) * 4;
    int* woff   = (int*)wsb;                       wsb += (size_t)NN * 4 + 4;
    int* eidx   = (int*)wsb;                       wsb += (size_t)EE * 4;

    // ---- init + prep + CSR ----
    hipLaunchKernelGGL(k_init_h, dim3((NN * TT * 8 + 255) / 256), dim3(256), 0, stream,
                       h_in, emb_w, emb_b, time_emb, hbuf);
    hipLaunchKernelGGL(k_init_coord, dim3((NN * TT + 255) / 256), dim3(256), 0, stream,
                       x, coord, deg);
    {
        int tot = LL * (EDGE_WPACK + NODE_WPACK);
        hipLaunchKernelGGL(k_prep, dim3((tot + 255) / 256), dim3(256), 0, stream,
                           ew1, eb1, ew2, eb2, cw1, cb1, nw1, nb1, nw2, nb2, wpack);
    }
    hipLaunchKernelGGL(k_deg, dim3((EE + 255) / 256), dim3(256), 0, stream, edges, deg);
    hipLaunchKernelGGL(k_scan, dim3(1), dim3(256), 0, stream, deg, rowptr, woff);
    hipLaunchKernelGGL(k_scatter, dim3((EE + 255) / 256), dim3(256), 0, stream,
                       edges, woff, eidx);

    unsigned short* wpack_node0 = wpack + (size_t)LL * EDGE_WPACK;
    for (int l = 0; l < LL; l++) {
        hipLaunchKernelGGL(k_edge_mfma, dim3(EE / 128, TT / 2), dim3(256), 0, stream,
            hbuf, coord, edges, eattr,
            wpack + (size_t)l * EDGE_WPACK,
            cw2 + (size_t)l * 64,
            mbuf8, trans4);
        hipLaunchKernelGGL(k_gather, dim3(NN / 4), dim3(256), 0, stream,
            mbuf8, trans4, rowptr, eidx, maggb, coord);
        hipLaunchKernelGGL(k_node_mfma, dim3((NN * TT + 127) / 128), dim3(256), 0, stream,
            hbuf, maggb, wpack_node0 + (size_t)l * NODE_WPACK);
    }
    hipLaunchKernelGGL(k_final, dim3((FOUT * NN + 255) / 256), dim3(256), 0, stream,
        coord, theta, out);
}

// Round 14
// 399.646 us; speedup vs baseline: 1.0369x; 1.0369x over previous
//
#include <hip/hip_runtime.h>
#include <hip/hip_bf16.h>

#define NN 5000
#define TT 10
#define FOUT 8
#define HH 64
#define EE 80000
#define LL 4

#define STR1 136            // K=128 weight pack k-stride (u16)
#define STR2 72             // K=64 weight pack k-stride (u16)

// edge wpack section offsets (u16, per layer) — LDS [col][k] pack
#define EWT1 0              // 64*136 = 8704 : edge_w1 rows 0..127 [col][k]
#define EWT2 8704           // 64*72  = 4608 : edge_w2 [col][k]
#define ECT1 13312          // 64*72  = 4608 : coord_w1 [col][k]
#define ETL1 17920          // 64*8   = 512  : [col][8] = {w_rad, w_ea0, w_ea1, b1, 0..}
#define ETB2 18432          // 64*8   = 512  : {b2, 0..}
#define ETC1 18944          // 64*8   = 512  : {cb1, 0..}
#define EDGE_WPACK 19456    // u16 per layer (38912 B)

// node wpack sections
#define NWT1 0              // 8704 : node_w1 [col][k]; k in [64,128) sigma-permuted
#define NWT2 8704           // 4608 : node_w2 [col][k]
#define NTL1 13312          // 512  : {nb1,0..}
#define NTL2 13824          // 512  : {nb2,0..}
#define NODE_WPACK 14336    // u16 per layer (28672 B)

typedef __attribute__((ext_vector_type(8))) short short8;
typedef __attribute__((ext_vector_type(16))) float f32x16;

union FragU { short8 s; unsigned u[4]; unsigned short h[8]; };

__device__ __forceinline__ float silu_f(float x) {
    float e = __expf(-x);
    return x * __builtin_amdgcn_rcpf(1.0f + e);
}
__device__ __forceinline__ float bf2f(unsigned short u) {
    return __uint_as_float(((unsigned int)u) << 16);
}
__device__ __forceinline__ unsigned short f2bf(float x) {   // RNE
    unsigned int u = __float_as_uint(x);
    u += 0x7fffu + ((u >> 16) & 1u);
    return (unsigned short)(u >> 16);
}
__device__ __forceinline__ unsigned pkbf(float lo, float hi) {
    unsigned r;
    asm("v_cvt_pk_bf16_f32 %0, %1, %2" : "=v"(r) : "v"(lo), "v"(hi));
    return r;
}
__device__ __forceinline__ void plswap(unsigned &a, unsigned &b) {
    asm("v_permlane32_swap_b32 %0, %1" : "+v"(a), "+v"(b));
}

__device__ __forceinline__ void pack_silu(const f32x16& a0, const f32x16& a1, unsigned u[2][8]) {
    #pragma unroll
    for (int q = 0; q < 4; q++) {
        #pragma unroll
        for (int h = 0; h < 2; h++) {
            u[0][2*q+h] = pkbf(silu_f(a0[4*q+2*h]), silu_f(a0[4*q+2*h+1]));
            u[1][2*q+h] = pkbf(silu_f(a1[4*q+2*h]), silu_f(a1[4*q+2*h+1]));
        }
    }
}
__device__ __forceinline__ void pack_raw(const f32x16& a0, const f32x16& a1, unsigned u[2][8]) {
    #pragma unroll
    for (int q = 0; q < 4; q++) {
        #pragma unroll
        for (int h = 0; h < 2; h++) {
            u[0][2*q+h] = pkbf(a0[4*q+2*h], a0[4*q+2*h+1]);
            u[1][2*q+h] = pkbf(a1[4*q+2*h], a1[4*q+2*h+1]);
        }
    }
}
__device__ __forceinline__ void exch(unsigned u[2][8], short8 bx[4]) {
    #pragma unroll
    for (int kt = 0; kt < 4; kt++) {
        const int m = kt >> 1, kk = kt & 1;
        unsigned X  = u[m][4*kk],     Y  = u[m][4*kk+2];
        unsigned X2 = u[m][4*kk+1],   Y2 = u[m][4*kk+3];
        plswap(X, Y);
        plswap(X2, Y2);
        FragU f; f.u[0] = X; f.u[1] = X2; f.u[2] = Y; f.u[3] = Y2;
        bx[kt] = f.s;
    }
}

// ---------------------------------------------------------------- init (vectorized: 8 cols/thread)
__global__ __launch_bounds__(256) void k_init_h(
    const float* __restrict__ h_in, const float* __restrict__ emb_w,
    const float* __restrict__ emb_b, const float* __restrict__ time_emb,
    unsigned short* __restrict__ hbuf)
{
    int idx = blockIdx.x * 256 + threadIdx.x;   // over N*T*8
    if (idx >= NN * TT * 8) return;
    int g  = idx & 7;
    int nt = idx >> 3;
    int t  = nt % TT;
    int n  = nt / TT;
    int j0 = g * 8;
    float hv = h_in[n];
    short8 o;
    #pragma unroll
    for (int jj = 0; jj < 8; jj++) {
        float val = hv * emb_w[j0 + jj] + emb_b[j0 + jj] + time_emb[t * 64 + j0 + jj];
        o[jj] = (short)f2bf(val);
    }
    *(short8*)(hbuf + (size_t)nt * 64 + j0) = o;
}

// also zeroes deg[] (runs before k_deg)
__global__ __launch_bounds__(256) void k_init_coord(
    const float* __restrict__ x, float* __restrict__ coord, int* __restrict__ deg)
{
    int i = blockIdx.x * 256 + threadIdx.x;
    if (i >= NN * TT) return;
    if (i < NN) deg[i] = 0;
    int t = i % TT, n = i / TT;
    const float* src = x + (size_t)(t * NN + n) * 3;
    float4 v;
    v.x = src[0]; v.y = src[1]; v.z = src[2]; v.w = 0.0f;
    *(float4*)(coord + (size_t)i * 4) = v;
}

// ---------------------------------------------------------------- weight prep (LDS-order pack)
__global__ __launch_bounds__(256) void k_prep(
    const float* __restrict__ ew1, const float* __restrict__ eb1,
    const float* __restrict__ ew2, const float* __restrict__ eb2,
    const float* __restrict__ cw1, const float* __restrict__ cb1,
    const float* __restrict__ nw1, const float* __restrict__ nb1,
    const float* __restrict__ nw2, const float* __restrict__ nb2,
    unsigned short* __restrict__ wpack)
{
    const int ETOT = LL * EDGE_WPACK;
    const int TOT  = ETOT + LL * NODE_WPACK;
    int idx = blockIdx.x * 256 + threadIdx.x;
    if (idx >= TOT) return;
    float v = 0.0f;
    if (idx < ETOT) {
        int l = idx / EDGE_WPACK, o = idx % EDGE_WPACK;
        if (o < EWT2) {
            int cc = o / STR1, k = o % STR1;
            if (k < 128) v = ew1[(size_t)l * 131 * 64 + (size_t)k * 64 + cc];
        } else if (o < ECT1) {
            int o2 = o - EWT2; int cc = o2 / STR2, k = o2 % STR2;
            if (k < 64) v = ew2[(size_t)l * 4096 + (size_t)k * 64 + cc];
        } else if (o < ETL1) {
            int o2 = o - ECT1; int cc = o2 / STR2, k = o2 % STR2;
            if (k < 64) v = cw1[(size_t)l * 4096 + (size_t)k * 64 + cc];
        } else if (o < ETB2) {
            int o2 = o - ETL1; int cc = o2 >> 3, j = o2 & 7;
            if (j == 0) v = ew1[(size_t)l * 131 * 64 + 128 * 64 + cc];
            else if (j == 1) v = ew1[(size_t)l * 131 * 64 + 129 * 64 + cc];
            else if (j == 2) v = ew1[(size_t)l * 131 * 64 + 130 * 64 + cc];
            else if (j == 3) v = eb1[l * 64 + cc];
        } else if (o < ETC1) {
            int o2 = o - ETB2; int cc = o2 >> 3, j = o2 & 7;
            if (j == 0) v = eb2[l * 64 + cc];
        } else {
            int o2 = o - ETC1; int cc = o2 >> 3, j = o2 & 7;
            if (j == 0) v = cb1[l * 64 + cc];
        }
    } else {
        int q = idx - ETOT;
        int l = q / NODE_WPACK, o = q % NODE_WPACK;
        if (o < NWT2) {
            int cc = o / STR1, k = o % STR1;
            if (k < 64) {
                v = nw1[(size_t)l * 8192 + (size_t)k * 64 + cc];
            } else if (k < 128) {
                int p = k - 64;
                int gp = p >> 5, mt = (p >> 4) & 1, reg = p & 15;
                int j = mt * 32 + (reg & 3) + 8 * (reg >> 2) + 4 * gp;
                v = nw1[(size_t)l * 8192 + (size_t)(64 + j) * 64 + cc];
            }
        } else if (o < NTL1) {
            int o2 = o - NWT2; int cc = o2 / STR2, k = o2 % STR2;
            if (k < 64) v = nw2[(size_t)l * 4096 + (size_t)k * 64 + cc];
        } else if (o < NTL2) {
            int o2 = o - NTL1; int cc = o2 >> 3, j = o2 & 7;
            if (j == 0) v = nb1[l * 64 + cc];
        } else {
            int o2 = o - NTL2; int cc = o2 >> 3, j = o2 & 7;
            if (j == 0) v = nb2[l * 64 + cc];
        }
    }
    wpack[idx] = f2bf(v);
}

// ---------------------------------------------------------------- CSR build
__global__ __launch_bounds__(256) void k_deg(
    const int* __restrict__ edges, int* __restrict__ deg)
{
    int e = blockIdx.x * 256 + threadIdx.x;
    if (e >= EE) return;
    atomicAdd(deg + edges[e], 1);
}

__global__ __launch_bounds__(256) void k_scan(
    const int* __restrict__ deg, int* __restrict__ rowptr, int* __restrict__ woff)
{
    __shared__ int sums[256];
    int tid = threadIdx.x;
    const int CH = (NN + 255) / 256;  // 20
    int base = tid * CH;
    int s = 0;
    for (int i = 0; i < CH; i++) {
        int idx = base + i;
        if (idx < NN) s += deg[idx];
    }
    sums[tid] = s;
    __syncthreads();
    for (int off = 1; off < 256; off <<= 1) {
        int other = (tid >= off) ? sums[tid - off] : 0;
        __syncthreads();
        sums[tid] += other;
        __syncthreads();
    }
    int run = sums[tid] - s;
    for (int i = 0; i < CH; i++) {
        int idx = base + i;
        if (idx < NN) {
            rowptr[idx] = run;
            woff[idx] = run;
            run += deg[idx];
        }
    }
    if (tid == 255) rowptr[NN] = run;
}

__global__ __launch_bounds__(256) void k_scatter(
    const int* __restrict__ edges, int* __restrict__ woff, int* __restrict__ eidx)
{
    int e = blockIdx.x * 256 + threadIdx.x;
    if (e >= EE) return;
    int pos = atomicAdd(woff + edges[e], 1);
    eidx[pos] = e;
}

// ---------------------------------------------------------------- edge MLP, 32x32x16 MFMA, LDS weights, T-paired
// grid (EE/128, TT/2): each wave does 32 edges x 2 timesteps; every weight ds_read feeds 2 MFMAs.
__global__ __launch_bounds__(256) void k_edge_mfma(
    const unsigned short* __restrict__ hbuf,  // bf16 [N*T][64]
    const float* __restrict__ coord,          // [N*T][4]
    const int* __restrict__ edges,
    const float* __restrict__ eattr,
    const unsigned short* __restrict__ wpack, // this layer's packed weights
    const float* __restrict__ cw2v,           // [64] f32
    unsigned char* __restrict__ mbuf8,        // fp8 e4m3 [E*T][64] (sigma-order)
    float* __restrict__ trans4)               // f32 [E*T][4]
{
    __shared__ __align__(16) unsigned short w_lds[EDGE_WPACK];
    __shared__ float cw2_lds[64];
    int tid = threadIdx.x;
    {
        const uint4* src = (const uint4*)wpack;
        uint4* dst = (uint4*)w_lds;
        #pragma unroll
        for (int i = 0; i < 10; i++) {
            int p = i * 256 + tid;
            if (p < EDGE_WPACK / 8) dst[p] = src[p];
        }
        if (tid < 64) cw2_lds[tid] = cw2v[tid];
    }
    __syncthreads();

    int wave = tid >> 6, lane = tid & 63;
    int gp = lane >> 5, c = lane & 31;
    bool g0 = (gp == 0);

    int e = blockIdx.x * 128 + wave * 32 + c;
    int t0 = blockIdx.y * 2;
    int rn = edges[e], cn = edges[EE + e];
    int rt0 = rn * TT + t0, ct0 = cn * TT + t0;
    int rt1 = rt0 + 1,      ct1 = ct0 + 1;

    float4 cr0 = *(const float4*)(coord + (size_t)rt0 * 4);
    float4 cl0 = *(const float4*)(coord + (size_t)ct0 * 4);
    float4 cr1 = *(const float4*)(coord + (size_t)rt1 * 4);
    float4 cl1 = *(const float4*)(coord + (size_t)ct1 * 4);
    float d00 = cr0.x - cl0.x, d01 = cr0.y - cl0.y, d02 = cr0.z - cl0.z;
    float d10 = cr1.x - cl1.x, d11 = cr1.y - cl1.y, d12 = cr1.z - cl1.z;
    float rad0 = d00 * d00 + d01 * d01 + d02 * d02;
    float rad1 = d10 * d10 + d11 * d11 + d12 * d12;
    float2 ea = *(const float2*)(eattr + 2 * e);

    const unsigned short* hr0 = hbuf + (size_t)rt0 * 64;
    const unsigned short* hc0 = hbuf + (size_t)ct0 * 64;
    const unsigned short* hr1 = hbuf + (size_t)rt1 * 64;
    const unsigned short* hc1 = hbuf + (size_t)ct1 * 64;
    short8 bh0[8], bh1[8];
    #pragma unroll
    for (int kt = 0; kt < 4; kt++) {
        bh0[kt]     = *(const short8*)(hr0 + kt * 16 + gp * 8);
        bh0[4 + kt] = *(const short8*)(hc0 + kt * 16 + gp * 8);
        bh1[kt]     = *(const short8*)(hr1 + kt * 16 + gp * 8);
        bh1[4 + kt] = *(const short8*)(hc1 + kt * 16 + gp * 8);
    }

    FragU btail0, btail1, bone;
    btail0.u[0] = btail0.u[1] = btail0.u[2] = btail0.u[3] = 0;
    btail1.u[0] = btail1.u[1] = btail1.u[2] = btail1.u[3] = 0;
    bone.u[0] = bone.u[1] = bone.u[2] = bone.u[3] = 0;
    if (g0) {
        btail0.u[0] = pkbf(rad0, ea.x); btail0.u[1] = pkbf(ea.y, 1.0f);
        btail1.u[0] = pkbf(rad1, ea.x); btail1.u[1] = pkbf(ea.y, 1.0f);
        bone.u[0] = 0x3F80u;
    }

    // ---- layer 1: K=128 + tail tile; each af ds_read feeds t0 and t1 ----
    f32x16 a0[2], a1[2];
    {
        f32x16 z = {};
        a0[0] = z; a0[1] = z; a1[0] = z; a1[1] = z;
    }
    #pragma unroll
    for (int kt = 0; kt < 8; kt++) {
        #pragma unroll
        for (int mt = 0; mt < 2; mt++) {
            short8 af = *(const short8*)&w_lds[EWT1 + (mt * 32 + c) * STR1 + kt * 16 + gp * 8];
            a0[mt] = __builtin_amdgcn_mfma_f32_32x32x16_bf16(af, bh0[kt], a0[mt], 0, 0, 0);
            a1[mt] = __builtin_amdgcn_mfma_f32_32x32x16_bf16(af, bh1[kt], a1[mt], 0, 0, 0);
        }
    }
    #pragma unroll
    for (int mt = 0; mt < 2; mt++) {
        short8 af = *(const short8*)&w_lds[ETL1 + (mt * 32 + c) * 8];
        a0[mt] = __builtin_amdgcn_mfma_f32_32x32x16_bf16(af, btail0.s, a0[mt], 0, 0, 0);
        a1[mt] = __builtin_amdgcn_mfma_f32_32x32x16_bf16(af, btail1.s, a1[mt], 0, 0, 0);
    }

    unsigned u[2][8];
    short8 bx0[4], bx1[4];
    pack_silu(a0[0], a0[1], u);
    exch(u, bx0);
    pack_silu(a1[0], a1[1], u);
    exch(u, bx1);

    // ---- layer 2: K=64 + bias tile ----
    f32x16 b0[2], b1[2];
    {
        f32x16 z = {};
        b0[0] = z; b0[1] = z; b1[0] = z; b1[1] = z;
    }
    #pragma unroll
    for (int kt = 0; kt < 4; kt++) {
        #pragma unroll
        for (int mt = 0; mt < 2; mt++) {
            short8 af = *(const short8*)&w_lds[EWT2 + (mt * 32 + c) * STR2 + kt * 16 + gp * 8];
            b0[mt] = __builtin_amdgcn_mfma_f32_32x32x16_bf16(af, bx0[kt], b0[mt], 0, 0, 0);
            b1[mt] = __builtin_amdgcn_mfma_f32_32x32x16_bf16(af, bx1[kt], b1[mt], 0, 0, 0);
        }
    }
    #pragma unroll
    for (int mt = 0; mt < 2; mt++) {
        short8 af = *(const short8*)&w_lds[ETB2 + (mt * 32 + c) * 8];
        b0[mt] = __builtin_amdgcn_mfma_f32_32x32x16_bf16(af, bone.s, b0[mt], 0, 0, 0);
        b1[mt] = __builtin_amdgcn_mfma_f32_32x32x16_bf16(af, bone.s, b1[mt], 0, 0, 0);
    }

    // ---- silu(m), b3 frags + fp8 store, per t ----
    short8 b30[4], b31[4];
    {
        float sv[2][16];
        #pragma unroll
        for (int mt = 0; mt < 2; mt++)
            #pragma unroll
            for (int r = 0; r < 16; r++) sv[mt][r] = silu_f(b0[mt][r]);
        #pragma unroll
        for (int q = 0; q < 4; q++)
            #pragma unroll
            for (int h = 0; h < 2; h++) {
                u[0][2*q+h] = pkbf(sv[0][4*q+2*h], sv[0][4*q+2*h+1]);
                u[1][2*q+h] = pkbf(sv[1][4*q+2*h], sv[1][4*q+2*h+1]);
            }
        exch(u, b30);
        unsigned w8[8];
        #pragma unroll
        for (int mt = 0; mt < 2; mt++)
            #pragma unroll
            for (int q = 0; q < 4; q++) {
                unsigned v = __builtin_amdgcn_cvt_pk_fp8_f32(sv[mt][4*q],   sv[mt][4*q+1], 0, false);
                v          = __builtin_amdgcn_cvt_pk_fp8_f32(sv[mt][4*q+2], sv[mt][4*q+3], v, true);
                w8[mt * 4 + q] = v;
            }
        unsigned char* mp8 = mbuf8 + ((size_t)e * TT + t0) * 64 + gp * 32;
        *(uint4*)(mp8)      = *(uint4*)&w8[0];
        *(uint4*)(mp8 + 16) = *(uint4*)&w8[4];
    }
    {
        float sv[2][16];
        #pragma unroll
        for (int mt = 0; mt < 2; mt++)
            #pragma unroll
            for (int r = 0; r < 16; r++) sv[mt][r] = silu_f(b1[mt][r]);
        #pragma unroll
        for (int q = 0; q < 4; q++)
            #pragma unroll
            for (int h = 0; h < 2; h++) {
                u[0][2*q+h] = pkbf(sv[0][4*q+2*h], sv[0][4*q+2*h+1]);
                u[1][2*q+h] = pkbf(sv[1][4*q+2*h], sv[1][4*q+2*h+1]);
            }
        exch(u, b31);
        unsigned w8[8];
        #pragma unroll
        for (int mt = 0; mt < 2; mt++)
            #pragma unroll
            for (int q = 0; q < 4; q++) {
                unsigned v = __builtin_amdgcn_cvt_pk_fp8_f32(sv[mt][4*q],   sv[mt][4*q+1], 0, false);
                v          = __builtin_amdgcn_cvt_pk_fp8_f32(sv[mt][4*q+2], sv[mt][4*q+3], v, true);
                w8[mt * 4 + q] = v;
            }
        unsigned char* mp8 = mbuf8 + ((size_t)e * TT + t0 + 1) * 64 + gp * 32;
        *(uint4*)(mp8)      = *(uint4*)&w8[0];
        *(uint4*)(mp8 + 16) = *(uint4*)&w8[4];
    }

    // ---- coord MLP, shared ds_reads ----
    f32x16 c0[2], c1[2];
    {
        f32x16 z = {};
        c0[0] = z; c0[1] = z; c1[0] = z; c1[1] = z;
    }
    #pragma unroll
    for (int kt = 0; kt < 4; kt++) {
        #pragma unroll
        for (int mt = 0; mt < 2; mt++) {
            short8 af = *(const short8*)&w_lds[ECT1 + (mt * 32 + c) * STR2 + kt * 16 + gp * 8];
            c0[mt] = __builtin_amdgcn_mfma_f32_32x32x16_bf16(af, b30[kt], c0[mt], 0, 0, 0);
            c1[mt] = __builtin_amdgcn_mfma_f32_32x32x16_bf16(af, b31[kt], c1[mt], 0, 0, 0);
        }
    }
    #pragma unroll
    for (int mt = 0; mt < 2; mt++) {
        short8 af = *(const short8*)&w_lds[ETC1 + (mt * 32 + c) * 8];
        c0[mt] = __builtin_amdgcn_mfma_f32_32x32x16_bf16(af, bone.s, c0[mt], 0, 0, 0);
        c1[mt] = __builtin_amdgcn_mfma_f32_32x32x16_bf16(af, bone.s, c1[mt], 0, 0, 0);
    }
    float p0 = 0.0f, p1 = 0.0f;
    #pragma unroll
    for (int mt = 0; mt < 2; mt++) {
        #pragma unroll
        for (int q = 0; q < 4; q++) {
            float4 w4 = *(const float4*)&cw2_lds[mt * 32 + 8 * q + 4 * gp];
            p0 += silu_f(c0[mt][4*q+0]) * w4.x;
            p0 += silu_f(c0[mt][4*q+1]) * w4.y;
            p0 += silu_f(c0[mt][4*q+2]) * w4.z;
            p0 += silu_f(c0[mt][4*q+3]) * w4.w;
            p1 += silu_f(c1[mt][4*q+0]) * w4.x;
            p1 += silu_f(c1[mt][4*q+1]) * w4.y;
            p1 += silu_f(c1[mt][4*q+2]) * w4.z;
            p1 += silu_f(c1[mt][4*q+3]) * w4.w;
        }
    }
    p0 += __shfl_xor(p0, 32);
    p1 += __shfl_xor(p1, 32);
    if (g0) {
        float4 o0; o0.x = d00 * p0; o0.y = d01 * p0; o0.z = d02 * p0; o0.w = 0.0f;
        float4 o1; o1.x = d10 * p1; o1.y = d11 * p1; o1.z = d12 * p1; o1.w = 0.0f;
        *(float4*)(trans4 + ((size_t)e * TT + t0) * 4)     = o0;
        *(float4*)(trans4 + ((size_t)e * TT + t0 + 1) * 4) = o1;
    }
}

// ---------------------------------------------------------------- gather: wave per node, all T fused (4-unrolled)
__global__ __launch_bounds__(256) void k_gather(
    const unsigned char* __restrict__ mbuf8, const float* __restrict__ trans4,
    const int* __restrict__ rowptr, const int* __restrict__ eidx,
    unsigned short* __restrict__ maggb, float* __restrict__ coord)
{
    int wv = __builtin_amdgcn_readfirstlane((int)(threadIdx.x >> 6));
    int lane = threadIdx.x & 63;
    int n = blockIdx.x * 4 + wv;
    int start = rowptr[n], end = rowptr[n + 1];

    bool ism = lane < 40;
    int tl = lane - 40; if (tl < 0) tl = 0; if (tl > 9) tl = 9;
    size_t moff = (size_t)lane * 16;
    size_t toff = (size_t)tl * 16;

    float acc[16];
    #pragma unroll
    for (int j = 0; j < 16; j++) acc[j] = 0.0f;
    float4 p4; p4.x = p4.y = p4.z = p4.w = 0.0f;

    int i = start;
    for (; i + 4 <= end; i += 4) {
        uint4 v[4];
        #pragma unroll
        for (int s = 0; s < 4; s++) {
            int ee = eidx[i + s];
            const char* a = ism ? (const char*)mbuf8 + (size_t)ee * 640 + moff
                                : (const char*)trans4 + (size_t)ee * 160 + toff;
            v[s] = *(const uint4*)a;
        }
        if (ism) {
            #pragma unroll
            for (int s = 0; s < 4; s++) {
                const unsigned* w0 = (const unsigned*)&v[s];
                #pragma unroll
                for (int w = 0; w < 4; w++) {
                    acc[w*4+0] += __builtin_amdgcn_cvt_f32_fp8(w0[w], 0);
                    acc[w*4+1] += __builtin_amdgcn_cvt_f32_fp8(w0[w], 1);
                    acc[w*4+2] += __builtin_amdgcn_cvt_f32_fp8(w0[w], 2);
                    acc[w*4+3] += __builtin_amdgcn_cvt_f32_fp8(w0[w], 3);
                }
            }
        } else {
            #pragma unroll
            for (int s = 0; s < 4; s++) {
                const float* f0 = (const float*)&v[s];
                p4.x += f0[0]; p4.y += f0[1]; p4.z += f0[2]; p4.w += f0[3];
            }
        }
    }
    for (; i < end; i++) {
        int e0 = eidx[i];
        const char* a0 = ism ? (const char*)mbuf8 + (size_t)e0 * 640 + moff
                             : (const char*)trans4 + (size_t)e0 * 160 + toff;
        uint4 v0 = *(const uint4*)a0;
        if (ism) {
            const unsigned* w0 = (const unsigned*)&v0;
            #pragma unroll
            for (int w = 0; w < 4; w++) {
                acc[w*4+0] += __builtin_amdgcn_cvt_f32_fp8(w0[w], 0);
                acc[w*4+1] += __builtin_amdgcn_cvt_f32_fp8(w0[w], 1);
                acc[w*4+2] += __builtin_amdgcn_cvt_f32_fp8(w0[w], 2);
                acc[w*4+3] += __builtin_amdgcn_cvt_f32_fp8(w0[w], 3);
            }
        } else {
            const float* f0 = (const float*)&v0;
            p4.x += f0[0]; p4.y += f0[1]; p4.z += f0[2]; p4.w += f0[3];
        }
    }

    if (ism) {
        unsigned w8[8];
        #pragma unroll
        for (int j = 0; j < 8; j++) w8[j] = pkbf(acc[2*j], acc[2*j+1]);
        unsigned short* dst = maggb + (size_t)n * 640 + lane * 16;
        *(uint4*)(dst)     = *(uint4*)&w8[0];
        *(uint4*)(dst + 8) = *(uint4*)&w8[4];
    } else if (lane < 50) {
        int t = lane - 40;
        float inv = 1.0f / fmaxf((float)(end - start), 1.0f);
        float* cp = coord + ((size_t)n * TT + t) * 4;
        float4 cv = *(float4*)cp;
        cv.x += p4.x * inv; cv.y += p4.y * inv; cv.z += p4.z * inv;
        *(float4*)cp = cv;
    }
}

// ---------------------------------------------------------------- node MLP, 32x32x16 MFMA, LDS weights
__global__ __launch_bounds__(256) void k_node_mfma(
    unsigned short* __restrict__ hbuf,
    const unsigned short* __restrict__ maggb,   // sigma-order (weights pre-permuted)
    const unsigned short* __restrict__ wpack)
{
    __shared__ __align__(16) unsigned short w_lds[NODE_WPACK];
    int tid = threadIdx.x;
    {
        const uint4* src = (const uint4*)wpack;
        uint4* dst = (uint4*)w_lds;
        #pragma unroll
        for (int i = 0; i < 7; i++) dst[i * 256 + tid] = src[i * 256 + tid];  // 1792 exact
    }
    __syncthreads();

    int wave = tid >> 6, lane = tid & 63;
    int gp = lane >> 5, c = lane & 31;
    bool g0 = (gp == 0);

    int idx = blockIdx.x * 128 + wave * 32 + c;
    bool valid = idx < NN * TT;
    int row = valid ? idx : 0;
    const unsigned short* hp = hbuf + (size_t)row * 64;
    const unsigned short* mp = maggb + (size_t)row * 64;
    short8 bh[8];
    #pragma unroll
    for (int kt = 0; kt < 4; kt++) bh[kt]     = *(const short8*)(hp + kt * 16 + gp * 8);
    #pragma unroll
    for (int kt = 0; kt < 4; kt++) bh[4 + kt] = *(const short8*)(mp + kt * 16 + gp * 8);
    FragU bone; bone.u[0] = bone.u[1] = bone.u[2] = bone.u[3] = 0;
    if (g0) bone.u[0] = 0x3F80u;

    f32x16 acc[2];
    {
        f32x16 z = {};
        acc[0] = z; acc[1] = z;
    }
    #pragma unroll
    for (int kt = 0; kt < 8; kt++) {
        #pragma unroll
        for (int mt = 0; mt < 2; mt++) {
            short8 af = *(const short8*)&w_lds[NWT1 + (mt * 32 + c) * STR1 + kt * 16 + gp * 8];
            acc[mt] = __builtin_amdgcn_mfma_f32_32x32x16_bf16(af, bh[kt], acc[mt], 0, 0, 0);
        }
    }
    #pragma unroll
    for (int mt = 0; mt < 2; mt++) {
        short8 af = *(const short8*)&w_lds[NTL1 + (mt * 32 + c) * 8];
        acc[mt] = __builtin_amdgcn_mfma_f32_32x32x16_bf16(af, bone.s, acc[mt], 0, 0, 0);
    }
    unsigned u[2][8];
    pack_silu(acc[0], acc[1], u);
    short8 bx[4];
    exch(u, bx);

    f32x16 acc2[2];
    {
        f32x16 z = {};
        acc2[0] = z; acc2[1] = z;
    }
    #pragma unroll
    for (int kt = 0; kt < 4; kt++) {
        #pragma unroll
        for (int mt = 0; mt < 2; mt++) {
            short8 af = *(const short8*)&w_lds[NWT2 + (mt * 32 + c) * STR2 + kt * 16 + gp * 8];
            acc2[mt] = __builtin_amdgcn_mfma_f32_32x32x16_bf16(af, bx[kt], acc2[mt], 0, 0, 0);
        }
    }
    #pragma unroll
    for (int mt = 0; mt < 2; mt++) {
        short8 af = *(const short8*)&w_lds[NTL2 + (mt * 32 + c) * 8];
        acc2[mt] = __builtin_amdgcn_mfma_f32_32x32x16_bf16(af, bone.s, acc2[mt], 0, 0, 0);
    }
    pack_raw(acc2[0], acc2[1], u);
    short8 o3[4];
    exch(u, o3);
    if (valid) {
        #pragma unroll
        for (int kt = 0; kt < 4; kt++) {
            FragU hv; hv.s = bh[kt];
            FragU of; of.s = o3[kt];
            FragU res;
            #pragma unroll
            for (int d = 0; d < 4; d++) {
                float a0 = bf2f(hv.h[2*d])   + bf2f((unsigned short)(of.u[d] & 0xFFFFu));
                float a1 = bf2f(hv.h[2*d+1]) + bf2f((unsigned short)(of.u[d] >> 16));
                res.u[d] = pkbf(a0, a1);
            }
            *(uint4*)(hbuf + (size_t)row * 64 + kt * 16 + gp * 8) = *(uint4*)res.u;
        }
    }
}

// ---------------------------------------------------------------- readout
__global__ __launch_bounds__(256) void k_final(
    const float* __restrict__ coord, const float* __restrict__ theta,
    float* __restrict__ out)
{
    int i = blockIdx.x * 256 + threadIdx.x;  // f*N + n
    if (i >= FOUT * NN) return;
    int f = i / NN, n = i % NN;

    float w[TT];
    float mx = -1e30f;
    #pragma unroll
    for (int t = 0; t < TT; t++) { w[t] = theta[f * TT + t]; mx = fmaxf(mx, w[t]); }
    float s = 0.0f;
    #pragma unroll
    for (int t = 0; t < TT; t++) { w[t] = __expf(w[t] - mx); s += w[t]; }
    float inv = 1.0f / s;
    float o0 = 0.f, o1 = 0.f, o2 = 0.f;
    #pragma unroll
    for (int t = 0; t < TT; t++) {
        float4 cv = *(const float4*)(coord + (size_t)(n * TT + t) * 4);
        float ww = w[t] * inv;
        o0 += ww * cv.x; o1 += ww * cv.y; o2 += ww * cv.z;
    }
    float* op = out + (size_t)(f * NN + n) * 3;
    op[0] = o0; op[1] = o1; op[2] = o2;
}

extern "C" void kernel_launch(void* const* d_in, const int* in_sizes, int n_in,
                              void* d_out, int out_size, void* d_ws, size_t ws_size,
                              hipStream_t stream)
{
    const float* h_in     = (const float*)d_in[0];
    const float* x        = (const float*)d_in[1];
    const int*   edges    = (const int*)d_in[2];
    const float* eattr    = (const float*)d_in[3];
    const float* emb_w    = (const float*)d_in[4];
    const float* emb_b    = (const float*)d_in[5];
    const float* time_emb = (const float*)d_in[6];
    const float* theta    = (const float*)d_in[7];
    const float* ew1 = (const float*)d_in[8];
    const float* eb1 = (const float*)d_in[9];
    const float* ew2 = (const float*)d_in[10];
    const float* eb2 = (const float*)d_in[11];
    const float* nw1 = (const float*)d_in[12];
    const float* nb1 = (const float*)d_in[13];
    const float* nw2 = (const float*)d_in[14];
    const float* nb2 = (const float*)d_in[15];
    const float* cw1 = (const float*)d_in[16];
    const float* cb1 = (const float*)d_in[17];
    const float* cw2 = (const float*)d_in[18];
    float* out = (float*)d_out;

    // ---- workspace carve ----
    char* wsb = (char*)d_ws;
    unsigned short* hbuf  = (unsigned short*)wsb;  wsb += (size_t)NN * TT * HH * 2;
    unsigned short* maggb = (unsigned short*)wsb;  wsb += (size_t)NN * TT * HH * 2;
    float* coord = (float*)wsb;                    wsb += (size_t)NN * TT * 4 * 4;
    unsigned char* mbuf8 = (unsigned char*)wsb;    wsb += (size_t)EE * TT * HH;      // fp8
    float* trans4 = (float*)wsb;                   wsb += (size_t)EE * TT * 4 * 4;
    unsigned short* wpack = (unsigned short*)wsb;  wsb += (size_t)LL * (EDGE_WPACK + NODE_WPACK) * 2;
    int* deg    = (int*)wsb;                       wsb += (size_t)NN * 4;
    int* rowptr = (int*)wsb;                       wsb += (size_t)(NN + 1) * 4;
    int* woff   = (int*)wsb;                       wsb += (size_t)NN * 4 + 4;
    int* eidx   = (int*)wsb;                       wsb += (size_t)EE * 4;

    // ---- init + prep + CSR ----
    hipLaunchKernelGGL(k_init_h, dim3((NN * TT * 8 + 255) / 256), dim3(256), 0, stream,
                       h_in, emb_w, emb_b, time_emb, hbuf);
    hipLaunchKernelGGL(k_init_coord, dim3((NN * TT + 255) / 256), dim3(256), 0, stream,
                       x, coord, deg);
    {
        int tot = LL * (EDGE_WPACK + NODE_WPACK);
        hipLaunchKernelGGL(k_prep, dim3((tot + 255) / 256), dim3(256), 0, stream,
                           ew1, eb1, ew2, eb2, cw1, cb1, nw1, nb1, nw2, nb2, wpack);
    }
    hipLaunchKernelGGL(k_deg, dim3((EE + 255) / 256), dim3(256), 0, stream, edges, deg);
    hipLaunchKernelGGL(k_scan, dim3(1), dim3(256), 0, stream, deg, rowptr, woff);
    hipLaunchKernelGGL(k_scatter, dim3((EE + 255) / 256), dim3(256), 0, stream,
                       edges, woff, eidx);

    unsigned short* wpack_node0 = wpack + (size_t)LL * EDGE_WPACK;
    for (int l = 0; l < LL; l++) {
        hipLaunchKernelGGL(k_edge_mfma, dim3(EE / 128, TT / 2), dim3(256), 0, stream,
            hbuf, coord, edges, eattr,
            wpack + (size_t)l * EDGE_WPACK,
            cw2 + (size_t)l * 64,
            mbuf8, trans4);
        hipLaunchKernelGGL(k_gather, dim3(NN / 4), dim3(256), 0, stream,
            mbuf8, trans4, rowptr, eidx, maggb, coord);
        hipLaunchKernelGGL(k_node_mfma, dim3((NN * TT + 127) / 128), dim3(256), 0, stream,
            hbuf, maggb, wpack_node0 + (size_t)l * NODE_WPACK);
    }
    hipLaunchKernelGGL(k_final, dim3((FOUT * NN + 255) / 256), dim3(256), 0, stream,
        coord, theta, out);
}